// Round 14
// baseline (493.903 us; speedup 1.0000x reference)
//
#include <hip/hip_runtime.h>
#include <hip/hip_bf16.h>
#include <math.h>

#define BATCH 16384
#define LATD 256
#define OUTD 12
#define NE 16

typedef short bf16x8 __attribute__((ext_vector_type(8)));
typedef float f32x4 __attribute__((ext_vector_type(4)));
typedef unsigned short u16x8 __attribute__((ext_vector_type(8)));

__device__ __forceinline__ float elu_f(float x) { return x > 0.f ? x : expm1f(x); }
__device__ __forceinline__ float elu_fast(float x) { return x > 0.f ? x : (__expf(x) - 1.f); }

__device__ __forceinline__ unsigned short f2bf(float f) {
  union { float f; unsigned int u; } a; a.f = f;
  unsigned int u = a.u;
  unsigned int r = (u + 0x7FFFu + ((u >> 16) & 1u)) >> 16;
  return (unsigned short)r;
}
// packed RNE f32x2 -> bf16x2 via v_cvt_pk_bf16_f32
__device__ __forceinline__ unsigned int f2bf2(float lo, float hi) {
  __hip_bfloat162 h2 = __float22bfloat162_rn(make_float2(lo, hi));
  return *reinterpret_cast<unsigned int*>(&h2);
}
__device__ __forceinline__ float bf2f(unsigned short h) {
  union { unsigned int u; float f; } a; a.u = ((unsigned int)h) << 16;
  return a.f;
}

// XOR swizzle on byte address within a 512B-row tile (bank-conflict fix).
__device__ __forceinline__ int swz(int b) { return b ^ (((b >> 9) & 7) << 4); }

// lat16 layout: tiles of 128 rows; tile rb = row>>7; within tile, byte
// addr = swz((row&127)*512 + col*2). Tile stride 65536 B.

// ---------------- proprio encoder: 256 ->128 elu ->64 + LN -> lat16 cols 0..63 ----------------
__global__ __launch_bounds__(256) void k_proprio(
    const float* __restrict__ P,
    const float* __restrict__ W1, const float* __restrict__ B1,
    const float* __restrict__ W2, const float* __restrict__ B2,
    const float* __restrict__ G, const float* __restrict__ Bn,
    unsigned short* __restrict__ lat16) {
  __shared__ __align__(16) float a[32][256];
  __shared__ float h[32][128];
  __shared__ float d[32][64];
  __shared__ float mrow[32], irow[32];
  const int t = threadIdx.x;
  const size_t row0 = (size_t)blockIdx.x * 32;
  {
    const float4* s = (const float4*)(P + row0 * 256);
    float4* dd = (float4*)&a[0][0];
    #pragma unroll
    for (int i = 0; i < 8; i++) dd[t + i * 256] = s[t + i * 256];
  }
  __syncthreads();
  {
    const int c = t & 127, g0 = (t >> 7) * 16;
    float acc[16];
    #pragma unroll
    for (int i = 0; i < 16; i++) acc[i] = 0.f;
    for (int k = 0; k < 256; k++) {
      const float w = W1[k * 128 + c];
      #pragma unroll
      for (int i = 0; i < 16; i++) acc[i] += a[g0 + i][k] * w;
    }
    const float bb = B1[c];
    #pragma unroll
    for (int i = 0; i < 16; i++) h[g0 + i][c] = elu_f(acc[i] + bb);
  }
  __syncthreads();
  {
    const int c = t & 63, g0 = (t >> 6) * 8;
    float acc[8];
    #pragma unroll
    for (int i = 0; i < 8; i++) acc[i] = 0.f;
    for (int k = 0; k < 128; k++) {
      const float w = W2[k * 64 + c];
      #pragma unroll
      for (int i = 0; i < 8; i++) acc[i] += h[g0 + i][k] * w;
    }
    const float bb = B2[c];
    #pragma unroll
    for (int i = 0; i < 8; i++) d[g0 + i][c] = acc[i] + bb;
  }
  __syncthreads();
  if (t < 32) {
    float m = 0.f;
    for (int j = 0; j < 64; j++) m += d[t][j];
    m *= (1.f / 64.f);
    float v = 0.f;
    for (int j = 0; j < 64; j++) { float x = d[t][j] - m; v += x * x; }
    v *= (1.f / 64.f);
    mrow[t] = m; irow[t] = 1.f / sqrtf(v + 1e-5f);
  }
  __syncthreads();
  {
    const int r = t >> 3, ch = t & 7;
    const size_t grow = row0 + r;
    const size_t rb = grow >> 7;
    const int loc = (int)(grow & 127);
    const float mm = mrow[r], iv = irow[r];
    float e[8];
    #pragma unroll
    for (int q = 0; q < 8; q++) {
      const int c = ch * 8 + q;
      e[q] = (d[r][c] - mm) * iv * G[c] + Bn[c];
    }
    uint4 o;
    o.x = f2bf2(e[0], e[1]); o.y = f2bf2(e[2], e[3]);
    o.z = f2bf2(e[4], e[5]); o.w = f2bf2(e[6], e[7]);
    *(uint4*)((char*)lat16 + rb * 65536 + swz(loc * 512 + ch * 16)) = o;
  }
}

// ---------------- merged weight prep: wt1-3 transpose, cnnWb transpose, w4t, w2g ----------------
// cnnWb k-order: knew = m*32 + co  (conv writes convflat as [m][co]); kold = co*64 + m.
__global__ __launch_bounds__(256) void k_prep(
    const float* __restrict__ ew1, const float* __restrict__ ew2, const float* __restrict__ ew3,
    const float* __restrict__ ew4, const float* __restrict__ cnn_lin_w, const float* __restrict__ C2W,
    unsigned short* __restrict__ wt1, unsigned short* __restrict__ wt2, unsigned short* __restrict__ wt3,
    unsigned short* __restrict__ w4t, unsigned short* __restrict__ cnnWb, unsigned short* __restrict__ w2g) {
  __shared__ float tile[64][65];
  const int t = threadIdx.x;
  const int bid = blockIdx.x;
  if (bid < 768) {
    const int k0 = (bid & 3) * 64, j0 = ((bid >> 2) & 3) * 64;
    const int zl = bid >> 4;
    const int layer = zl >> 4, e = zl & 15;
    const float* src = (layer == 0 ? ew1 : layer == 1 ? ew2 : ew3) + (size_t)e * 65536;
    unsigned short* dst = (layer == 0 ? wt1 : layer == 1 ? wt2 : wt3) + (size_t)e * 65536;
    for (int idx = t; idx < 4096; idx += 256) {
      const int kk = idx >> 6, jj = idx & 63;
      tile[kk][jj] = src[(size_t)(k0 + kk) * 256 + j0 + jj];
    }
    __syncthreads();
    for (int idx = t; idx < 4096; idx += 256) {
      const int jj = idx >> 6, kk = idx & 63;
      dst[(size_t)(j0 + jj) * 256 + k0 + kk] = f2bf(tile[kk][jj]);
    }
  } else if (bid < 864) {
    const int idx0 = bid - 768;
    const int k0 = (idx0 & 31) * 64, j0 = (idx0 >> 5) * 64;
    for (int idx = t; idx < 4096; idx += 256) {
      const int kk = idx >> 6, jj = idx & 63;
      const int knew = k0 + kk;
      const int kold = (knew & 31) * 64 + (knew >> 5);
      tile[kk][jj] = cnn_lin_w[(size_t)kold * 192 + j0 + jj];
    }
    __syncthreads();
    for (int idx = t; idx < 4096; idx += 256) {
      const int jj = idx >> 6, kk = idx & 63;
      cnnWb[(size_t)(j0 + jj) * 2048 + k0 + kk] = f2bf(tile[kk][jj]);
    }
  } else if (bid < 880) {
    const int e = bid - 864, k = t;
    #pragma unroll
    for (int j = 0; j < 16; j++) {
      const float v = (j < 12) ? ew4[(size_t)e * 3072 + k * 12 + j] : 0.f;
      w4t[(size_t)e * 4096 + j * 256 + k] = f2bf(v);
    }
  } else {
    const int co = t >> 3, ci0 = t & 7;
    #pragma unroll
    for (int hh = 0; hh < 2; hh++) {
      const int ci = ci0 + hh * 8;
      #pragma unroll
      for (int tap = 0; tap < 16; tap++) {
        w2g[co * 256 + ci * 16 + tap] =
            (tap < 9) ? f2bf(C2W[co * 144 + ci * 9 + tap]) : (unsigned short)0;
      }
    }
  }
}

// ---------------- conv1 (VALU) + conv2 (implicit-GEMM MFMA) -> convflat bf16 [b][m*32+co] ----------------
// conv1 reads img as float4 (pitch 36: 2-way bank alias = free) -> 27 LDS reads/thread vs 51.
__global__ __launch_bounds__(256) void k_conv(
    const float* __restrict__ cam,
    const float* __restrict__ C1W, const float* __restrict__ C1B,
    const unsigned short* __restrict__ w2g, const float* __restrict__ C2B,
    unsigned short* __restrict__ flat) {
  __shared__ __align__(16) float img[32 * 36];               // pitch 36, cols 32-35 zero
  __shared__ float w1s[144];
  __shared__ __align__(16) unsigned short c1[16 * 17 * 20];  // [ci][17][20], row16+cols16-19 zero
  const int t = threadIdx.x;
  const int lane = t & 63, w = t >> 6;
  const int lr = lane & 15, lg = lane >> 4;
  const size_t b = blockIdx.x;
  char* c1b = (char*)c1;
  {
    const float* ip = cam + b * 1024;
    for (int i = t; i < 1024; i += 256) img[(i >> 5) * 36 + (i & 31)] = ip[i];
    if (t < 32) *(float4*)&img[t * 36 + 32] = make_float4(0.f, 0.f, 0.f, 0.f);
    if (t < 144) w1s[t] = C1W[t];
    if (t < 80) *(ushort4*)(c1b + (t / 5) * 680 + 640 + (t % 5) * 8) = make_ushort4(0, 0, 0, 0);
  }
  __syncthreads();
  {  // conv1: thread=(ch c, out-row y), 16 x outputs -> c1 bf16
    const int c = t >> 4, y = t & 15;
    float acc[16];
    #pragma unroll
    for (int x = 0; x < 16; x++) acc[x] = 0.f;
    #pragma unroll
    for (int dy = 0; dy < 3; dy++) {
      const int row = 2 * y + dy;
      if (row < 32) {
        float4 f4[9];
        #pragma unroll
        for (int i = 0; i < 9; i++) f4[i] = *(const float4*)&img[row * 36 + 4 * i];
        const float* rr = (const float*)f4;
        const float wa = w1s[c * 9 + dy * 3], wb = w1s[c * 9 + dy * 3 + 1], wc = w1s[c * 9 + dy * 3 + 2];
        #pragma unroll
        for (int x = 0; x < 16; x++) acc[x] += wa * rr[2 * x] + wb * rr[2 * x + 1] + wc * rr[2 * x + 2];
      }
    }
    const float bb = C1B[c];
    #pragma unroll
    for (int p = 0; p < 4; p++) {
      uint2 v;
      v.x = f2bf2(elu_fast(acc[4 * p + 0] + bb), elu_fast(acc[4 * p + 1] + bb));
      v.y = f2bf2(elu_fast(acc[4 * p + 2] + bb), elu_fast(acc[4 * p + 3] + bb));
      *(uint2*)(c1b + c * 680 + y * 40 + p * 8) = v;
    }
    *(ushort4*)(c1b + c * 680 + y * 40 + 32) = make_ushort4(0, 0, 0, 0);
  }
  __syncthreads();
  {  // GEMM: out[co 32][m 64] = w2g . B^T ; B-fragment built in regs from c1.
    f32x4 acc[2];
    acc[0] = (f32x4){0.f, 0.f, 0.f, 0.f};
    acc[1] = (f32x4){0.f, 0.f, 0.f, 0.f};
    const int m = w * 16 + lr;
    const int y = m >> 3, x = m & 7;
    const int ciq = lg >> 1, half = lg & 1;
    const int rbase = 2 * y;
    #pragma unroll
    for (int ks = 0; ks < 8; ks++) {
      const int ci = 2 * ks + ciq;
      const int base = ci * 680 + 4 * x;
      union { uint4 u; bf16x8 v; } B;
      if (half == 0) {
        const unsigned int pr0 = *(const unsigned int*)(c1b + base + (rbase + 0) * 40);
        const unsigned short t0 = *(const unsigned short*)(c1b + base + (rbase + 0) * 40 + 4);
        const unsigned int pr1 = *(const unsigned int*)(c1b + base + (rbase + 1) * 40);
        const unsigned short t1 = *(const unsigned short*)(c1b + base + (rbase + 1) * 40 + 4);
        const unsigned int pr2 = *(const unsigned int*)(c1b + base + (rbase + 2) * 40);
        B.u.x = pr0;
        B.u.y = (unsigned int)t0 | ((pr1 & 0xFFFFu) << 16);
        B.u.z = (pr1 >> 16) | ((unsigned int)t1 << 16);
        B.u.w = pr2;
      } else {
        const unsigned short t2 = *(const unsigned short*)(c1b + base + (rbase + 2) * 40 + 4);
        B.u = make_uint4((unsigned int)t2, 0u, 0u, 0u);
      }
      #pragma unroll
      for (int nt = 0; nt < 2; nt++) {
        const bf16x8 af = *(const bf16x8*)(w2g + (nt * 16 + lr) * 256 + ks * 32 + lg * 8);
        acc[nt] = __builtin_amdgcn_mfma_f32_16x16x32_bf16(af, B.v, acc[nt], 0, 0, 0);
      }
    }
    #pragma unroll
    for (int nt = 0; nt < 2; nt++) {
      const float4 bb = *(const float4*)(C2B + nt * 16 + 4 * lg);
      uint2 v;
      v.x = f2bf2(elu_fast(acc[nt][0] + bb.x), elu_fast(acc[nt][1] + bb.y));
      v.y = f2bf2(elu_fast(acc[nt][2] + bb.z), elu_fast(acc[nt][3] + bb.w));
      *(uint2*)(flat + b * 2048 + (size_t)m * 32 + nt * 16 + 4 * lg) = v;
    }
  }
}

// ---------------- cnn linear via MFMA: BM=32, full batch (512 blocks), +bias, LN ----------------
__global__ __launch_bounds__(256) void k_cnnlin(
    const unsigned short* __restrict__ Xc, const unsigned short* __restrict__ Wb,
    const float* __restrict__ bias, const float* __restrict__ G,
    const float* __restrict__ Bn, unsigned short* __restrict__ lat16) {
  __shared__ __align__(16) unsigned short XS[32 * 256];
  __shared__ __align__(16) float Yl[32 * 196];
  __shared__ float mrow[32], irow[32];
  char* xsb = (char*)XS;
  const int t = threadIdx.x;
  const int lane = t & 63, w = t >> 6;
  const int lr = lane & 15, lg = lane >> 4;
  const int b0 = blockIdx.x * 32;
  const int j0w = w * 48;

  f32x4 acc[3][2];
  #pragma unroll
  for (int jt = 0; jt < 3; jt++)
    #pragma unroll
    for (int mt = 0; mt < 2; mt++) acc[jt][mt] = (f32x4){0.f, 0.f, 0.f, 0.f};

  for (int kc = 0; kc < 8; kc++) {
    #pragma unroll
    for (int i = 0; i < 4; i++) {
      const int f = t + i * 256;
      const int m = f >> 5;
      const int kof = (f & 31) * 8;
      const u16x8 v = *(const u16x8*)(Xc + (size_t)(b0 + m) * 2048 + kc * 256 + kof);
      *(u16x8*)(xsb + swz(m * 512 + kof * 2)) = v;
    }
    __syncthreads();
    #pragma unroll
    for (int ks = 0; ks < 8; ks++) {
      bf16x8 af[3], bfr[2];
      #pragma unroll
      for (int jt = 0; jt < 3; jt++)
        af[jt] = *(const bf16x8*)(Wb + (size_t)(j0w + jt * 16 + lr) * 2048 + kc * 256 + ks * 32 + lg * 8);
      #pragma unroll
      for (int mt = 0; mt < 2; mt++)
        bfr[mt] = *(const bf16x8*)(xsb + swz((mt * 16 + lr) * 512 + lg * 16 + ks * 64));
      #pragma unroll
      for (int jt = 0; jt < 3; jt++)
        #pragma unroll
        for (int mt = 0; mt < 2; mt++)
          acc[jt][mt] = __builtin_amdgcn_mfma_f32_16x16x32_bf16(af[jt], bfr[mt], acc[jt][mt], 0, 0, 0);
    }
    __syncthreads();
  }
  #pragma unroll
  for (int jt = 0; jt < 3; jt++) {
    const int j0 = j0w + jt * 16 + 4 * lg;
    const float4 bb = *(const float4*)(bias + j0);
    #pragma unroll
    for (int mt = 0; mt < 2; mt++) {
      const int m = mt * 16 + lr;
      f32x4 v = acc[jt][mt];
      v[0] += bb.x; v[1] += bb.y; v[2] += bb.z; v[3] += bb.w;
      *(f32x4*)&Yl[m * 196 + j0] = v;
    }
  }
  __syncthreads();
  if (t < 32) {
    float m = 0.f;
    for (int q = 0; q < 48; q++) {
      const f32x4 v = *(const f32x4*)&Yl[t * 196 + q * 4];
      m += v[0] + v[1] + v[2] + v[3];
    }
    m *= (1.f / 192.f);
    float var = 0.f;
    for (int q = 0; q < 48; q++) {
      const f32x4 v = *(const f32x4*)&Yl[t * 196 + q * 4];
      #pragma unroll
      for (int z = 0; z < 4; z++) { const float x = v[z] - m; var += x * x; }
    }
    var *= (1.f / 192.f);
    mrow[t] = m; irow[t] = 1.f / sqrtf(var + 1e-5f);
  }
  __syncthreads();
  {
    #pragma unroll
    for (int i = 0; i < 3; i++) {
      const int item = t + i * 256;
      const int m = item / 24, cq = item % 24;
      const float mm = mrow[m], iv = irow[m];
      float e[8];
      #pragma unroll
      for (int q = 0; q < 8; q++) {
        const int j = cq * 8 + q;
        e[q] = (Yl[m * 196 + j] - mm) * iv * G[j] + Bn[j];
      }
      uint4 o;
      o.x = f2bf2(e[0], e[1]); o.y = f2bf2(e[2], e[3]);
      o.z = f2bf2(e[4], e[5]); o.w = f2bf2(e[6], e[7]);
      const size_t grow = (size_t)(b0 + m);
      const size_t rb = grow >> 7;
      const int loc = (int)(grow & 127);
      *(uint4*)((char*)lat16 + rb * 65536 + swz(loc * 512 + 128 + cq * 16)) = o;
    }
  }
}

// ---------------- router: reads bf16 lat16 ----------------
__global__ __launch_bounds__(256) void k_router(
    const unsigned short* __restrict__ lat16,
    const float* __restrict__ W1, const float* __restrict__ B1,
    const float* __restrict__ W2, const float* __restrict__ B2,
    const float* __restrict__ W3, const float* __restrict__ B3,
    float* __restrict__ gate) {
  __shared__ __align__(16) float a[32][256];
  __shared__ float h1[32][128];
  __shared__ float h2[32][64];
  __shared__ float lg[32][16];
  const int t = threadIdx.x;
  const size_t row0 = (size_t)blockIdx.x * 32;
  {
    #pragma unroll
    for (int i = 0; i < 4; i++) {
      const int cc = t + i * 256;
      const int r = cc >> 5, kc = cc & 31;
      const size_t grow = row0 + r;
      const size_t rb = grow >> 7;
      const int loc = (int)(grow & 127);
      const u16x8 h = *(const u16x8*)((const char*)lat16 + rb * 65536 + swz(loc * 512 + kc * 16));
      #pragma unroll
      for (int q = 0; q < 8; q++) a[r][kc * 8 + q] = bf2f(h[q]);
    }
  }
  __syncthreads();
  {
    const int c = t & 127, g0 = (t >> 7) * 16;
    float acc[16];
    #pragma unroll
    for (int i = 0; i < 16; i++) acc[i] = 0.f;
    for (int k = 0; k < 256; k++) {
      const float w = W1[k * 128 + c];
      #pragma unroll
      for (int i = 0; i < 16; i++) acc[i] += a[g0 + i][k] * w;
    }
    const float bb = B1[c];
    #pragma unroll
    for (int i = 0; i < 16; i++) h1[g0 + i][c] = elu_f(acc[i] + bb);
  }
  __syncthreads();
  {
    const int c = t & 63, g0 = (t >> 6) * 8;
    float acc[8];
    #pragma unroll
    for (int i = 0; i < 8; i++) acc[i] = 0.f;
    for (int k = 0; k < 128; k++) {
      const float w = W2[k * 64 + c];
      #pragma unroll
      for (int i = 0; i < 8; i++) acc[i] += h1[g0 + i][k] * w;
    }
    const float bb = B2[c];
    #pragma unroll
    for (int i = 0; i < 8; i++) h2[g0 + i][c] = elu_f(acc[i] + bb);
  }
  __syncthreads();
  for (int o = t; o < 512; o += 256) {
    const int r = o >> 4, c = o & 15;
    float acc = 0.f;
    for (int k = 0; k < 64; k++) acc += h2[r][k] * W3[k * 16 + c];
    lg[r][c] = acc + B3[c];
  }
  __syncthreads();
  if (t < 32) {
    float m = lg[t][0];
    for (int c = 1; c < 16; c++) m = fmaxf(m, lg[t][c]);
    float s = 0.f;
    float ex[16];
    for (int c = 0; c < 16; c++) { ex[c] = expf(lg[t][c] - m); s += ex[c]; }
    const float inv = 1.f / s;
    for (int c = 0; c < 16; c++) gate[(row0 + t) * 16 + c] = ex[c] * inv;
  }
}

// ---------------- experts: round-11 4-wave (j64 x m64), single 32KB X, in-place (control) ----------------
__global__ __launch_bounds__(256) void k_experts(
    const unsigned short* __restrict__ lat16, const float* __restrict__ gate,
    const unsigned short* __restrict__ wt1, const unsigned short* __restrict__ wt2,
    const unsigned short* __restrict__ wt3, const unsigned short* __restrict__ w4t,
    const float* __restrict__ EB1, const float* __restrict__ EB2,
    const float* __restrict__ EB3, const float* __restrict__ EB4,
    float* __restrict__ eout, int e_base) {
  __shared__ __align__(16) unsigned short X[64 * 256];  // 32KB, in-place across layers
  char* sx = (char*)X;
  const int t = threadIdx.x;
  const int lane = t & 63, w = t >> 6;
  const int lr = lane & 15, lg = lane >> 4;
  const int bid = blockIdx.x;
  const int xcd = bid & 7, l = bid >> 3;
  const int e = e_base + (l >> 5);
  const int rb = xcd * 32 + (l & 31);
  const int row0 = rb * 64;

  const float gv = gate[(size_t)(row0 + w * 16 + lr) * 16 + e];

  {
    const uint4* s = (const uint4*)(lat16 + (size_t)(rb >> 1) * 32768 + (size_t)(rb & 1) * 16384);
    uint4* dd = (uint4*)X;
    #pragma unroll
    for (int i = 0; i < 8; i++) dd[t + i * 256] = s[t + i * 256];
  }
  __syncthreads();

  const unsigned short* Wl[3] = {
    wt1 + (size_t)e * 65536, wt2 + (size_t)e * 65536, wt3 + (size_t)e * 65536 };
  const float* Bl[3] = { EB1 + e * 256, EB2 + e * 256, EB3 + e * 256 };
  const int wjb = w * 64;

  int mtb[4];
  #pragma unroll
  for (int mt = 0; mt < 4; mt++) mtb[mt] = (mt * 16 + lr) * 512 + lg * 16;

  #pragma unroll
  for (int lyr = 0; lyr < 3; lyr++) {
    const unsigned short* W = Wl[lyr];
    const float* B = Bl[lyr];
    f32x4 acc[4][4];
    #pragma unroll
    for (int jt = 0; jt < 4; jt++) {
      const float4 bb = *(const float4*)(B + wjb + jt * 16 + 4 * lg);
      #pragma unroll
      for (int mt = 0; mt < 4; mt++)
        acc[jt][mt] = (f32x4){bb.x, bb.y, bb.z, bb.w};
    }
    const size_t wlane = (size_t)(wjb + lr) * 256 + lg * 8;
    for (int ks = 0; ks < 8; ks++) {
      bf16x8 af[4], bfr[4];
      #pragma unroll
      for (int jt = 0; jt < 4; jt++)
        af[jt] = *(const bf16x8*)(W + wlane + jt * 4096 + ks * 32);
      #pragma unroll
      for (int mt = 0; mt < 4; mt++)
        bfr[mt] = *(const bf16x8*)(sx + swz(mtb[mt] + ks * 64));
      __builtin_amdgcn_s_setprio(1);
      #pragma unroll
      for (int jt = 0; jt < 4; jt++)
        #pragma unroll
        for (int mt = 0; mt < 4; mt++)
          acc[jt][mt] = __builtin_amdgcn_mfma_f32_16x16x32_bf16(af[jt], bfr[mt], acc[jt][mt], 0, 0, 0);
      __builtin_amdgcn_s_setprio(0);
    }
    __syncthreads();
    #pragma unroll
    for (int jt = 0; jt < 4; jt++) {
      const int j0 = wjb + jt * 16 + 4 * lg;
      #pragma unroll
      for (int mt = 0; mt < 4; mt++) {
        const int m = mt * 16 + lr;
        ushort4 h;
        h.x = f2bf(elu_fast(acc[jt][mt][0]));
        h.y = f2bf(elu_fast(acc[jt][mt][1]));
        h.z = f2bf(elu_fast(acc[jt][mt][2]));
        h.w = f2bf(elu_fast(acc[jt][mt][3]));
        *(ushort4*)(sx + swz(m * 512 + j0 * 2)) = h;
      }
    }
    __syncthreads();
  }

  {
    const unsigned short* W4 = w4t + (size_t)e * 4096;
    float4 b4 = make_float4(0.f, 0.f, 0.f, 0.f);
    if (lg < 3) b4 = *(const float4*)(EB4 + e * 12 + 4 * lg);
    f32x4 a4 = (f32x4){b4.x, b4.y, b4.z, b4.w};
    const size_t wl4 = (size_t)lr * 256 + lg * 8;
    const int mb = (w * 16 + lr) * 512 + lg * 16;
    #pragma unroll
    for (int ks = 0; ks < 8; ks++) {
      const bf16x8 a = *(const bf16x8*)(W4 + wl4 + ks * 32);
      const bf16x8 bv = *(const bf16x8*)(sx + swz(mb + ks * 64));
      a4 = __builtin_amdgcn_mfma_f32_16x16x32_bf16(a, bv, a4, 0, 0, 0);
    }
    const int row = row0 + w * 16 + lr;
    if (lg < 3) {
      float4 o;
      o.x = gv * a4[0];
      o.y = gv * a4[1];
      o.z = gv * a4[2];
      o.w = gv * a4[3];
      *(float4*)(eout + ((size_t)e * BATCH + row) * 12 + 4 * lg) = o;
    }
  }
}

__global__ __launch_bounds__(256) void k_reduce(
    const float* __restrict__ eout, float* __restrict__ out) {
  const int i = blockIdx.x * 256 + threadIdx.x;
  if (i < BATCH * OUTD) {
    float s = 0.f;
    #pragma unroll
    for (int e = 0; e < NE; e++) s += eout[(size_t)e * (BATCH * OUTD) + i];
    out[i] = s;
  }
}

extern "C" void kernel_launch(void* const* d_in, const int* in_sizes, int n_in,
                              void* d_out, int out_size, void* d_ws, size_t ws_size,
                              hipStream_t stream) {
  (void)in_sizes; (void)n_in; (void)out_size; (void)ws_size;
  const float* proprio   = (const float*)d_in[0];
  const float* camera    = (const float*)d_in[1];
  const float* enc_w1    = (const float*)d_in[2];
  const float* enc_b1    = (const float*)d_in[3];
  const float* enc_w2    = (const float*)d_in[4];
  const float* enc_b2    = (const float*)d_in[5];
  const float* enc_ln_g  = (const float*)d_in[6];
  const float* enc_ln_b  = (const float*)d_in[7];
  const float* conv1_w   = (const float*)d_in[8];
  const float* conv1_b   = (const float*)d_in[9];
  const float* conv2_w   = (const float*)d_in[10];
  const float* conv2_b   = (const float*)d_in[11];
  const float* cnn_lin_w = (const float*)d_in[12];
  const float* cnn_lin_b = (const float*)d_in[13];
  const float* cnn_ln_g  = (const float*)d_in[14];
  const float* cnn_ln_b  = (const float*)d_in[15];
  const float* rw1 = (const float*)d_in[16];
  const float* rb1 = (const float*)d_in[17];
  const float* rw2 = (const float*)d_in[18];
  const float* rb2 = (const float*)d_in[19];
  const float* rw3 = (const float*)d_in[20];
  const float* rb3 = (const float*)d_in[21];
  const float* ew1 = (const float*)d_in[22];
  const float* eb1 = (const float*)d_in[23];
  const float* ew2 = (const float*)d_in[24];
  const float* eb2 = (const float*)d_in[25];
  const float* ew3 = (const float*)d_in[26];
  const float* eb3 = (const float*)d_in[27];
  const float* ew4 = (const float*)d_in[28];
  const float* eb4 = (const float*)d_in[29];
  float* out = (float*)d_out;

  // ws: lat16 8.4MB | gate 1MB | wt1-3+w4t 6.4MB | cnnWb 0.8MB | w2g 16KB |
  //     REGION (aliased): convflat bf16 67MB (dead after cnnlin) then eout f32 12.6MB
  unsigned short* lat16 = (unsigned short*)d_ws;
  float* gate = (float*)(lat16 + (size_t)BATCH * 256);
  unsigned short* wt1 = (unsigned short*)(gate + (size_t)BATCH * NE);
  unsigned short* wt2 = wt1 + (size_t)NE * 65536;
  unsigned short* wt3 = wt2 + (size_t)NE * 65536;
  unsigned short* w4t = wt3 + (size_t)NE * 65536;
  unsigned short* cnnWb = w4t + (size_t)NE * 4096;
  unsigned short* w2g = cnnWb + (size_t)192 * 2048;
  unsigned short* region = w2g + (size_t)32 * 256;
  unsigned short* convflat = region;
  float* eout = (float*)region;

  k_prep<<<dim3(881), dim3(256), 0, stream>>>(ew1, ew2, ew3, ew4, cnn_lin_w, conv2_w,
                                              wt1, wt2, wt3, w4t, cnnWb, w2g);
  k_proprio<<<dim3(512), dim3(256), 0, stream>>>(proprio, enc_w1, enc_b1, enc_w2, enc_b2,
                                                 enc_ln_g, enc_ln_b, lat16);
  k_conv<<<dim3(16384), dim3(256), 0, stream>>>(camera, conv1_w, conv1_b, w2g, conv2_b, convflat);
  k_cnnlin<<<dim3(512), dim3(256), 0, stream>>>(convflat, cnnWb, cnn_lin_b,
                                                cnn_ln_g, cnn_ln_b, lat16);
  k_router<<<dim3(512), dim3(256), 0, stream>>>(lat16, rw1, rb1, rw2, rb2, rw3, rb3, gate);
  k_experts<<<dim3(2048), dim3(256), 0, stream>>>(lat16, gate, wt1, wt2, wt3, w4t,
                                                  eb1, eb2, eb3, eb4, eout, 0);
  k_experts<<<dim3(2048), dim3(256), 0, stream>>>(lat16, gate, wt1, wt2, wt3, w4t,
                                                  eb1, eb2, eb3, eb4, eout, 8);
  k_reduce<<<dim3(768), dim3(256), 0, stream>>>(eout, out);
}

// Round 15
// 489.414 us; speedup vs baseline: 1.0092x; 1.0092x over previous
//
#include <hip/hip_runtime.h>
#include <hip/hip_bf16.h>
#include <math.h>

#define BATCH 16384
#define LATD 256
#define OUTD 12
#define NE 16

typedef short bf16x8 __attribute__((ext_vector_type(8)));
typedef float f32x4 __attribute__((ext_vector_type(4)));
typedef unsigned short u16x8 __attribute__((ext_vector_type(8)));

__device__ __forceinline__ float elu_f(float x) { return x > 0.f ? x : expm1f(x); }
__device__ __forceinline__ float elu_fast(float x) { return x > 0.f ? x : (__expf(x) - 1.f); }

__device__ __forceinline__ unsigned short f2bf(float f) {
  union { float f; unsigned int u; } a; a.f = f;
  unsigned int u = a.u;
  unsigned int r = (u + 0x7FFFu + ((u >> 16) & 1u)) >> 16;
  return (unsigned short)r;
}
// packed RNE f32x2 -> bf16x2 via v_cvt_pk_bf16_f32
__device__ __forceinline__ unsigned int f2bf2(float lo, float hi) {
  __hip_bfloat162 h2 = __float22bfloat162_rn(make_float2(lo, hi));
  return *reinterpret_cast<unsigned int*>(&h2);
}
__device__ __forceinline__ float bf2f(unsigned short h) {
  union { unsigned int u; float f; } a; a.u = ((unsigned int)h) << 16;
  return a.f;
}

// XOR swizzle on byte address within a 512B-row tile (bank-conflict fix).
__device__ __forceinline__ int swz(int b) { return b ^ (((b >> 9) & 7) << 4); }

// lat16 layout: tiles of 128 rows; tile rb = row>>7; within tile, byte
// addr = swz((row&127)*512 + col*2). Tile stride 65536 B.

// ---------------- proprio encoder: 256 ->128 elu ->64 + LN -> lat16 cols 0..63 ----------------
__global__ __launch_bounds__(256) void k_proprio(
    const float* __restrict__ P,
    const float* __restrict__ W1, const float* __restrict__ B1,
    const float* __restrict__ W2, const float* __restrict__ B2,
    const float* __restrict__ G, const float* __restrict__ Bn,
    unsigned short* __restrict__ lat16) {
  __shared__ __align__(16) float a[32][256];
  __shared__ float h[32][128];
  __shared__ float d[32][64];
  __shared__ float mrow[32], irow[32];
  const int t = threadIdx.x;
  const size_t row0 = (size_t)blockIdx.x * 32;
  {
    const float4* s = (const float4*)(P + row0 * 256);
    float4* dd = (float4*)&a[0][0];
    #pragma unroll
    for (int i = 0; i < 8; i++) dd[t + i * 256] = s[t + i * 256];
  }
  __syncthreads();
  {
    const int c = t & 127, g0 = (t >> 7) * 16;
    float acc[16];
    #pragma unroll
    for (int i = 0; i < 16; i++) acc[i] = 0.f;
    for (int k = 0; k < 256; k++) {
      const float w = W1[k * 128 + c];
      #pragma unroll
      for (int i = 0; i < 16; i++) acc[i] += a[g0 + i][k] * w;
    }
    const float bb = B1[c];
    #pragma unroll
    for (int i = 0; i < 16; i++) h[g0 + i][c] = elu_f(acc[i] + bb);
  }
  __syncthreads();
  {
    const int c = t & 63, g0 = (t >> 6) * 8;
    float acc[8];
    #pragma unroll
    for (int i = 0; i < 8; i++) acc[i] = 0.f;
    for (int k = 0; k < 128; k++) {
      const float w = W2[k * 64 + c];
      #pragma unroll
      for (int i = 0; i < 8; i++) acc[i] += h[g0 + i][k] * w;
    }
    const float bb = B2[c];
    #pragma unroll
    for (int i = 0; i < 8; i++) d[g0 + i][c] = acc[i] + bb;
  }
  __syncthreads();
  if (t < 32) {
    float m = 0.f;
    for (int j = 0; j < 64; j++) m += d[t][j];
    m *= (1.f / 64.f);
    float v = 0.f;
    for (int j = 0; j < 64; j++) { float x = d[t][j] - m; v += x * x; }
    v *= (1.f / 64.f);
    mrow[t] = m; irow[t] = 1.f / sqrtf(v + 1e-5f);
  }
  __syncthreads();
  {
    const int r = t >> 3, ch = t & 7;
    const size_t grow = row0 + r;
    const size_t rb = grow >> 7;
    const int loc = (int)(grow & 127);
    const float mm = mrow[r], iv = irow[r];
    float e[8];
    #pragma unroll
    for (int q = 0; q < 8; q++) {
      const int c = ch * 8 + q;
      e[q] = (d[r][c] - mm) * iv * G[c] + Bn[c];
    }
    uint4 o;
    o.x = f2bf2(e[0], e[1]); o.y = f2bf2(e[2], e[3]);
    o.z = f2bf2(e[4], e[5]); o.w = f2bf2(e[6], e[7]);
    *(uint4*)((char*)lat16 + rb * 65536 + swz(loc * 512 + ch * 16)) = o;
  }
}

// ---------------- merged weight prep: wt1-3 transpose, cnnWb transpose, w4t, w2g ----------------
// cnnWb k-order: knew = m*32 + co  (conv writes convflat as [m][co]); kold = co*64 + m.
__global__ __launch_bounds__(256) void k_prep(
    const float* __restrict__ ew1, const float* __restrict__ ew2, const float* __restrict__ ew3,
    const float* __restrict__ ew4, const float* __restrict__ cnn_lin_w, const float* __restrict__ C2W,
    unsigned short* __restrict__ wt1, unsigned short* __restrict__ wt2, unsigned short* __restrict__ wt3,
    unsigned short* __restrict__ w4t, unsigned short* __restrict__ cnnWb, unsigned short* __restrict__ w2g) {
  __shared__ float tile[64][65];
  const int t = threadIdx.x;
  const int bid = blockIdx.x;
  if (bid < 768) {
    const int k0 = (bid & 3) * 64, j0 = ((bid >> 2) & 3) * 64;
    const int zl = bid >> 4;
    const int layer = zl >> 4, e = zl & 15;
    const float* src = (layer == 0 ? ew1 : layer == 1 ? ew2 : ew3) + (size_t)e * 65536;
    unsigned short* dst = (layer == 0 ? wt1 : layer == 1 ? wt2 : wt3) + (size_t)e * 65536;
    for (int idx = t; idx < 4096; idx += 256) {
      const int kk = idx >> 6, jj = idx & 63;
      tile[kk][jj] = src[(size_t)(k0 + kk) * 256 + j0 + jj];
    }
    __syncthreads();
    for (int idx = t; idx < 4096; idx += 256) {
      const int jj = idx >> 6, kk = idx & 63;
      dst[(size_t)(j0 + jj) * 256 + k0 + kk] = f2bf(tile[kk][jj]);
    }
  } else if (bid < 864) {
    const int idx0 = bid - 768;
    const int k0 = (idx0 & 31) * 64, j0 = (idx0 >> 5) * 64;
    for (int idx = t; idx < 4096; idx += 256) {
      const int kk = idx >> 6, jj = idx & 63;
      const int knew = k0 + kk;
      const int kold = (knew & 31) * 64 + (knew >> 5);
      tile[kk][jj] = cnn_lin_w[(size_t)kold * 192 + j0 + jj];
    }
    __syncthreads();
    for (int idx = t; idx < 4096; idx += 256) {
      const int jj = idx >> 6, kk = idx & 63;
      cnnWb[(size_t)(j0 + jj) * 2048 + k0 + kk] = f2bf(tile[kk][jj]);
    }
  } else if (bid < 880) {
    const int e = bid - 864, k = t;
    #pragma unroll
    for (int j = 0; j < 16; j++) {
      const float v = (j < 12) ? ew4[(size_t)e * 3072 + k * 12 + j] : 0.f;
      w4t[(size_t)e * 4096 + j * 256 + k] = f2bf(v);
    }
  } else {
    const int co = t >> 3, ci0 = t & 7;
    #pragma unroll
    for (int hh = 0; hh < 2; hh++) {
      const int ci = ci0 + hh * 8;
      #pragma unroll
      for (int tap = 0; tap < 16; tap++) {
        w2g[co * 256 + ci * 16 + tap] =
            (tap < 9) ? f2bf(C2W[co * 144 + ci * 9 + tap]) : (unsigned short)0;
      }
    }
  }
}

// ---------------- conv1 (VALU) + conv2 (implicit-GEMM MFMA) -> convflat bf16 [b][m*32+co] ----------------
// Round-13 proven best: img pitch 34 + float2 reads; B-fragments in regs from c1; 3 barriers.
__global__ __launch_bounds__(256) void k_conv(
    const float* __restrict__ cam,
    const float* __restrict__ C1W, const float* __restrict__ C1B,
    const unsigned short* __restrict__ w2g, const float* __restrict__ C2B,
    unsigned short* __restrict__ flat) {
  __shared__ __align__(16) float img[32 * 34];               // pitch 34, cols 32-33 zero
  __shared__ float w1s[144];
  __shared__ __align__(16) unsigned short c1[16 * 17 * 20];  // [ci][17][20], row16+cols16-19 zero
  const int t = threadIdx.x;
  const int lane = t & 63, w = t >> 6;
  const int lr = lane & 15, lg = lane >> 4;
  const size_t b = blockIdx.x;
  char* c1b = (char*)c1;
  {
    const float* ip = cam + b * 1024;
    for (int i = t; i < 1024; i += 256) img[(i >> 5) * 34 + (i & 31)] = ip[i];
    if (t < 64) img[(t & 31) * 34 + 32 + (t >> 5)] = 0.f;
    if (t < 144) w1s[t] = C1W[t];
    if (t < 80) *(ushort4*)(c1b + (t / 5) * 680 + 640 + (t % 5) * 8) = make_ushort4(0, 0, 0, 0);
  }
  __syncthreads();
  {  // conv1: thread=(ch c, out-row y), 16 x outputs -> c1 bf16
    const int c = t >> 4, y = t & 15;
    float acc[16];
    #pragma unroll
    for (int x = 0; x < 16; x++) acc[x] = 0.f;
    #pragma unroll
    for (int dy = 0; dy < 3; dy++) {
      const int row = 2 * y + dy;
      if (row < 32) {
        float2 f[17];
        #pragma unroll
        for (int i = 0; i < 17; i++) f[i] = *(const float2*)&img[row * 34 + 2 * i];
        const float wa = w1s[c * 9 + dy * 3], wb = w1s[c * 9 + dy * 3 + 1], wc = w1s[c * 9 + dy * 3 + 2];
        #pragma unroll
        for (int x = 0; x < 16; x++) acc[x] += wa * f[x].x + wb * f[x].y + wc * f[x + 1].x;
      }
    }
    const float bb = C1B[c];
    #pragma unroll
    for (int p = 0; p < 4; p++) {
      uint2 v;
      v.x = f2bf2(elu_fast(acc[4 * p + 0] + bb), elu_fast(acc[4 * p + 1] + bb));
      v.y = f2bf2(elu_fast(acc[4 * p + 2] + bb), elu_fast(acc[4 * p + 3] + bb));
      *(uint2*)(c1b + c * 680 + y * 40 + p * 8) = v;
    }
    *(ushort4*)(c1b + c * 680 + y * 40 + 32) = make_ushort4(0, 0, 0, 0);
  }
  __syncthreads();
  {  // GEMM: out[co 32][m 64] = w2g . B^T ; B-fragment built in regs from c1.
    f32x4 acc[2];
    acc[0] = (f32x4){0.f, 0.f, 0.f, 0.f};
    acc[1] = (f32x4){0.f, 0.f, 0.f, 0.f};
    const int m = w * 16 + lr;
    const int y = m >> 3, x = m & 7;
    const int ciq = lg >> 1, half = lg & 1;
    const int rbase = 2 * y;
    #pragma unroll
    for (int ks = 0; ks < 8; ks++) {
      const int ci = 2 * ks + ciq;
      const int base = ci * 680 + 4 * x;
      union { uint4 u; bf16x8 v; } B;
      if (half == 0) {
        const unsigned int pr0 = *(const unsigned int*)(c1b + base + (rbase + 0) * 40);
        const unsigned short t0 = *(const unsigned short*)(c1b + base + (rbase + 0) * 40 + 4);
        const unsigned int pr1 = *(const unsigned int*)(c1b + base + (rbase + 1) * 40);
        const unsigned short t1 = *(const unsigned short*)(c1b + base + (rbase + 1) * 40 + 4);
        const unsigned int pr2 = *(const unsigned int*)(c1b + base + (rbase + 2) * 40);
        B.u.x = pr0;
        B.u.y = (unsigned int)t0 | ((pr1 & 0xFFFFu) << 16);
        B.u.z = (pr1 >> 16) | ((unsigned int)t1 << 16);
        B.u.w = pr2;
      } else {
        const unsigned short t2 = *(const unsigned short*)(c1b + base + (rbase + 2) * 40 + 4);
        B.u = make_uint4((unsigned int)t2, 0u, 0u, 0u);
      }
      #pragma unroll
      for (int nt = 0; nt < 2; nt++) {
        const bf16x8 af = *(const bf16x8*)(w2g + (nt * 16 + lr) * 256 + ks * 32 + lg * 8);
        acc[nt] = __builtin_amdgcn_mfma_f32_16x16x32_bf16(af, B.v, acc[nt], 0, 0, 0);
      }
    }
    #pragma unroll
    for (int nt = 0; nt < 2; nt++) {
      const float4 bb = *(const float4*)(C2B + nt * 16 + 4 * lg);
      uint2 v;
      v.x = f2bf2(elu_fast(acc[nt][0] + bb.x), elu_fast(acc[nt][1] + bb.y));
      v.y = f2bf2(elu_fast(acc[nt][2] + bb.z), elu_fast(acc[nt][3] + bb.w));
      *(uint2*)(flat + b * 2048 + (size_t)m * 32 + nt * 16 + 4 * lg) = v;
    }
  }
}

// ---------------- cnn linear via MFMA: BM=32, full batch (512 blocks), +bias, LN ----------------
__global__ __launch_bounds__(256) void k_cnnlin(
    const unsigned short* __restrict__ Xc, const unsigned short* __restrict__ Wb,
    const float* __restrict__ bias, const float* __restrict__ G,
    const float* __restrict__ Bn, unsigned short* __restrict__ lat16) {
  __shared__ __align__(16) unsigned short XS[32 * 256];
  __shared__ __align__(16) float Yl[32 * 196];
  __shared__ float mrow[32], irow[32];
  char* xsb = (char*)XS;
  const int t = threadIdx.x;
  const int lane = t & 63, w = t >> 6;
  const int lr = lane & 15, lg = lane >> 4;
  const int b0 = blockIdx.x * 32;
  const int j0w = w * 48;

  f32x4 acc[3][2];
  #pragma unroll
  for (int jt = 0; jt < 3; jt++)
    #pragma unroll
    for (int mt = 0; mt < 2; mt++) acc[jt][mt] = (f32x4){0.f, 0.f, 0.f, 0.f};

  for (int kc = 0; kc < 8; kc++) {
    #pragma unroll
    for (int i = 0; i < 4; i++) {
      const int f = t + i * 256;
      const int m = f >> 5;
      const int kof = (f & 31) * 8;
      const u16x8 v = *(const u16x8*)(Xc + (size_t)(b0 + m) * 2048 + kc * 256 + kof);
      *(u16x8*)(xsb + swz(m * 512 + kof * 2)) = v;
    }
    __syncthreads();
    #pragma unroll
    for (int ks = 0; ks < 8; ks++) {
      bf16x8 af[3], bfr[2];
      #pragma unroll
      for (int jt = 0; jt < 3; jt++)
        af[jt] = *(const bf16x8*)(Wb + (size_t)(j0w + jt * 16 + lr) * 2048 + kc * 256 + ks * 32 + lg * 8);
      #pragma unroll
      for (int mt = 0; mt < 2; mt++)
        bfr[mt] = *(const bf16x8*)(xsb + swz((mt * 16 + lr) * 512 + lg * 16 + ks * 64));
      #pragma unroll
      for (int jt = 0; jt < 3; jt++)
        #pragma unroll
        for (int mt = 0; mt < 2; mt++)
          acc[jt][mt] = __builtin_amdgcn_mfma_f32_16x16x32_bf16(af[jt], bfr[mt], acc[jt][mt], 0, 0, 0);
    }
    __syncthreads();
  }
  #pragma unroll
  for (int jt = 0; jt < 3; jt++) {
    const int j0 = j0w + jt * 16 + 4 * lg;
    const float4 bb = *(const float4*)(bias + j0);
    #pragma unroll
    for (int mt = 0; mt < 2; mt++) {
      const int m = mt * 16 + lr;
      f32x4 v = acc[jt][mt];
      v[0] += bb.x; v[1] += bb.y; v[2] += bb.z; v[3] += bb.w;
      *(f32x4*)&Yl[m * 196 + j0] = v;
    }
  }
  __syncthreads();
  if (t < 32) {
    float m = 0.f;
    for (int q = 0; q < 48; q++) {
      const f32x4 v = *(const f32x4*)&Yl[t * 196 + q * 4];
      m += v[0] + v[1] + v[2] + v[3];
    }
    m *= (1.f / 192.f);
    float var = 0.f;
    for (int q = 0; q < 48; q++) {
      const f32x4 v = *(const f32x4*)&Yl[t * 196 + q * 4];
      #pragma unroll
      for (int z = 0; z < 4; z++) { const float x = v[z] - m; var += x * x; }
    }
    var *= (1.f / 192.f);
    mrow[t] = m; irow[t] = 1.f / sqrtf(var + 1e-5f);
  }
  __syncthreads();
  {
    #pragma unroll
    for (int i = 0; i < 3; i++) {
      const int item = t + i * 256;
      const int m = item / 24, cq = item % 24;
      const float mm = mrow[m], iv = irow[m];
      float e[8];
      #pragma unroll
      for (int q = 0; q < 8; q++) {
        const int j = cq * 8 + q;
        e[q] = (Yl[m * 196 + j] - mm) * iv * G[j] + Bn[j];
      }
      uint4 o;
      o.x = f2bf2(e[0], e[1]); o.y = f2bf2(e[2], e[3]);
      o.z = f2bf2(e[4], e[5]); o.w = f2bf2(e[6], e[7]);
      const size_t grow = (size_t)(b0 + m);
      const size_t rb = grow >> 7;
      const int loc = (int)(grow & 127);
      *(uint4*)((char*)lat16 + rb * 65536 + swz(loc * 512 + 128 + cq * 16)) = o;
    }
  }
}

// ---------------- router: reads bf16 lat16 ----------------
__global__ __launch_bounds__(256) void k_router(
    const unsigned short* __restrict__ lat16,
    const float* __restrict__ W1, const float* __restrict__ B1,
    const float* __restrict__ W2, const float* __restrict__ B2,
    const float* __restrict__ W3, const float* __restrict__ B3,
    float* __restrict__ gate) {
  __shared__ __align__(16) float a[32][256];
  __shared__ float h1[32][128];
  __shared__ float h2[32][64];
  __shared__ float lg[32][16];
  const int t = threadIdx.x;
  const size_t row0 = (size_t)blockIdx.x * 32;
  {
    #pragma unroll
    for (int i = 0; i < 4; i++) {
      const int cc = t + i * 256;
      const int r = cc >> 5, kc = cc & 31;
      const size_t grow = row0 + r;
      const size_t rb = grow >> 7;
      const int loc = (int)(grow & 127);
      const u16x8 h = *(const u16x8*)((const char*)lat16 + rb * 65536 + swz(loc * 512 + kc * 16));
      #pragma unroll
      for (int q = 0; q < 8; q++) a[r][kc * 8 + q] = bf2f(h[q]);
    }
  }
  __syncthreads();
  {
    const int c = t & 127, g0 = (t >> 7) * 16;
    float acc[16];
    #pragma unroll
    for (int i = 0; i < 16; i++) acc[i] = 0.f;
    for (int k = 0; k < 256; k++) {
      const float w = W1[k * 128 + c];
      #pragma unroll
      for (int i = 0; i < 16; i++) acc[i] += a[g0 + i][k] * w;
    }
    const float bb = B1[c];
    #pragma unroll
    for (int i = 0; i < 16; i++) h1[g0 + i][c] = elu_f(acc[i] + bb);
  }
  __syncthreads();
  {
    const int c = t & 63, g0 = (t >> 6) * 8;
    float acc[8];
    #pragma unroll
    for (int i = 0; i < 8; i++) acc[i] = 0.f;
    for (int k = 0; k < 128; k++) {
      const float w = W2[k * 64 + c];
      #pragma unroll
      for (int i = 0; i < 8; i++) acc[i] += h1[g0 + i][k] * w;
    }
    const float bb = B2[c];
    #pragma unroll
    for (int i = 0; i < 8; i++) h2[g0 + i][c] = elu_f(acc[i] + bb);
  }
  __syncthreads();
  for (int o = t; o < 512; o += 256) {
    const int r = o >> 4, c = o & 15;
    float acc = 0.f;
    for (int k = 0; k < 64; k++) acc += h2[r][k] * W3[k * 16 + c];
    lg[r][c] = acc + B3[c];
  }
  __syncthreads();
  if (t < 32) {
    float m = lg[t][0];
    for (int c = 1; c < 16; c++) m = fmaxf(m, lg[t][c]);
    float s = 0.f;
    float ex[16];
    for (int c = 0; c < 16; c++) { ex[c] = expf(lg[t][c] - m); s += ex[c]; }
    const float inv = 1.f / s;
    for (int c = 0; c < 16; c++) gate[(row0 + t) * 16 + c] = ex[c] * inv;
  }
}

// ---------------- experts: round-11 4-wave (j64 x m64), single 32KB X, in-place (control) ----------------
__global__ __launch_bounds__(256) void k_experts(
    const unsigned short* __restrict__ lat16, const float* __restrict__ gate,
    const unsigned short* __restrict__ wt1, const unsigned short* __restrict__ wt2,
    const unsigned short* __restrict__ wt3, const unsigned short* __restrict__ w4t,
    const float* __restrict__ EB1, const float* __restrict__ EB2,
    const float* __restrict__ EB3, const float* __restrict__ EB4,
    float* __restrict__ eout, int e_base) {
  __shared__ __align__(16) unsigned short X[64 * 256];  // 32KB, in-place across layers
  char* sx = (char*)X;
  const int t = threadIdx.x;
  const int lane = t & 63, w = t >> 6;
  const int lr = lane & 15, lg = lane >> 4;
  const int bid = blockIdx.x;
  const int xcd = bid & 7, l = bid >> 3;
  const int e = e_base + (l >> 5);
  const int rb = xcd * 32 + (l & 31);
  const int row0 = rb * 64;

  const float gv = gate[(size_t)(row0 + w * 16 + lr) * 16 + e];

  {
    const uint4* s = (const uint4*)(lat16 + (size_t)(rb >> 1) * 32768 + (size_t)(rb & 1) * 16384);
    uint4* dd = (uint4*)X;
    #pragma unroll
    for (int i = 0; i < 8; i++) dd[t + i * 256] = s[t + i * 256];
  }
  __syncthreads();

  const unsigned short* Wl[3] = {
    wt1 + (size_t)e * 65536, wt2 + (size_t)e * 65536, wt3 + (size_t)e * 65536 };
  const float* Bl[3] = { EB1 + e * 256, EB2 + e * 256, EB3 + e * 256 };
  const int wjb = w * 64;

  int mtb[4];
  #pragma unroll
  for (int mt = 0; mt < 4; mt++) mtb[mt] = (mt * 16 + lr) * 512 + lg * 16;

  #pragma unroll
  for (int lyr = 0; lyr < 3; lyr++) {
    const unsigned short* W = Wl[lyr];
    const float* B = Bl[lyr];
    f32x4 acc[4][4];
    #pragma unroll
    for (int jt = 0; jt < 4; jt++) {
      const float4 bb = *(const float4*)(B + wjb + jt * 16 + 4 * lg);
      #pragma unroll
      for (int mt = 0; mt < 4; mt++)
        acc[jt][mt] = (f32x4){bb.x, bb.y, bb.z, bb.w};
    }
    const size_t wlane = (size_t)(wjb + lr) * 256 + lg * 8;
    for (int ks = 0; ks < 8; ks++) {
      bf16x8 af[4], bfr[4];
      #pragma unroll
      for (int jt = 0; jt < 4; jt++)
        af[jt] = *(const bf16x8*)(W + wlane + jt * 4096 + ks * 32);
      #pragma unroll
      for (int mt = 0; mt < 4; mt++)
        bfr[mt] = *(const bf16x8*)(sx + swz(mtb[mt] + ks * 64));
      __builtin_amdgcn_s_setprio(1);
      #pragma unroll
      for (int jt = 0; jt < 4; jt++)
        #pragma unroll
        for (int mt = 0; mt < 4; mt++)
          acc[jt][mt] = __builtin_amdgcn_mfma_f32_16x16x32_bf16(af[jt], bfr[mt], acc[jt][mt], 0, 0, 0);
      __builtin_amdgcn_s_setprio(0);
    }
    __syncthreads();
    #pragma unroll
    for (int jt = 0; jt < 4; jt++) {
      const int j0 = wjb + jt * 16 + 4 * lg;
      #pragma unroll
      for (int mt = 0; mt < 4; mt++) {
        const int m = mt * 16 + lr;
        ushort4 h;
        h.x = f2bf(elu_fast(acc[jt][mt][0]));
        h.y = f2bf(elu_fast(acc[jt][mt][1]));
        h.z = f2bf(elu_fast(acc[jt][mt][2]));
        h.w = f2bf(elu_fast(acc[jt][mt][3]));
        *(ushort4*)(sx + swz(m * 512 + j0 * 2)) = h;
      }
    }
    __syncthreads();
  }

  {
    const unsigned short* W4 = w4t + (size_t)e * 4096;
    float4 b4 = make_float4(0.f, 0.f, 0.f, 0.f);
    if (lg < 3) b4 = *(const float4*)(EB4 + e * 12 + 4 * lg);
    f32x4 a4 = (f32x4){b4.x, b4.y, b4.z, b4.w};
    const size_t wl4 = (size_t)lr * 256 + lg * 8;
    const int mb = (w * 16 + lr) * 512 + lg * 16;
    #pragma unroll
    for (int ks = 0; ks < 8; ks++) {
      const bf16x8 a = *(const bf16x8*)(W4 + wl4 + ks * 32);
      const bf16x8 bv = *(const bf16x8*)(sx + swz(mb + ks * 64));
      a4 = __builtin_amdgcn_mfma_f32_16x16x32_bf16(a, bv, a4, 0, 0, 0);
    }
    const int row = row0 + w * 16 + lr;
    if (lg < 3) {
      float4 o;
      o.x = gv * a4[0];
      o.y = gv * a4[1];
      o.z = gv * a4[2];
      o.w = gv * a4[3];
      *(float4*)(eout + ((size_t)e * BATCH + row) * 12 + 4 * lg) = o;
    }
  }
}

__global__ __launch_bounds__(256) void k_reduce(
    const float* __restrict__ eout, float* __restrict__ out) {
  const int i = blockIdx.x * 256 + threadIdx.x;
  if (i < BATCH * OUTD) {
    float s = 0.f;
    #pragma unroll
    for (int e = 0; e < NE; e++) s += eout[(size_t)e * (BATCH * OUTD) + i];
    out[i] = s;
  }
}

extern "C" void kernel_launch(void* const* d_in, const int* in_sizes, int n_in,
                              void* d_out, int out_size, void* d_ws, size_t ws_size,
                              hipStream_t stream) {
  (void)in_sizes; (void)n_in; (void)out_size; (void)ws_size;
  const float* proprio   = (const float*)d_in[0];
  const float* camera    = (const float*)d_in[1];
  const float* enc_w1    = (const float*)d_in[2];
  const float* enc_b1    = (const float*)d_in[3];
  const float* enc_w2    = (const float*)d_in[4];
  const float* enc_b2    = (const float*)d_in[5];
  const float* enc_ln_g  = (const float*)d_in[6];
  const float* enc_ln_b  = (const float*)d_in[7];
  const float* conv1_w   = (const float*)d_in[8];
  const float* conv1_b   = (const float*)d_in[9];
  const float* conv2_w   = (const float*)d_in[10];
  const float* conv2_b   = (const float*)d_in[11];
  const float* cnn_lin_w = (const float*)d_in[12];
  const float* cnn_lin_b = (const float*)d_in[13];
  const float* cnn_ln_g  = (const float*)d_in[14];
  const float* cnn_ln_b  = (const float*)d_in[15];
  const float* rw1 = (const float*)d_in[16];
  const float* rb1 = (const float*)d_in[17];
  const float* rw2 = (const float*)d_in[18];
  const float* rb2 = (const float*)d_in[19];
  const float* rw3 = (const float*)d_in[20];
  const float* rb3 = (const float*)d_in[21];
  const float* ew1 = (const float*)d_in[22];
  const float* eb1 = (const float*)d_in[23];
  const float* ew2 = (const float*)d_in[24];
  const float* eb2 = (const float*)d_in[25];
  const float* ew3 = (const float*)d_in[26];
  const float* eb3 = (const float*)d_in[27];
  const float* ew4 = (const float*)d_in[28];
  const float* eb4 = (const float*)d_in[29];
  float* out = (float*)d_out;

  // ws: lat16 8.4MB | gate 1MB | wt1-3+w4t 6.4MB | cnnWb 0.8MB | w2g 16KB |
  //     REGION (aliased): convflat bf16 67MB (dead after cnnlin) then eout f32 12.6MB
  unsigned short* lat16 = (unsigned short*)d_ws;
  float* gate = (float*)(lat16 + (size_t)BATCH * 256);
  unsigned short* wt1 = (unsigned short*)(gate + (size_t)BATCH * NE);
  unsigned short* wt2 = wt1 + (size_t)NE * 65536;
  unsigned short* wt3 = wt2 + (size_t)NE * 65536;
  unsigned short* w4t = wt3 + (size_t)NE * 65536;
  unsigned short* cnnWb = w4t + (size_t)NE * 4096;
  unsigned short* w2g = cnnWb + (size_t)192 * 2048;
  unsigned short* region = w2g + (size_t)32 * 256;
  unsigned short* convflat = region;
  float* eout = (float*)region;

  k_prep<<<dim3(881), dim3(256), 0, stream>>>(ew1, ew2, ew3, ew4, cnn_lin_w, conv2_w,
                                              wt1, wt2, wt3, w4t, cnnWb, w2g);
  k_proprio<<<dim3(512), dim3(256), 0, stream>>>(proprio, enc_w1, enc_b1, enc_w2, enc_b2,
                                                 enc_ln_g, enc_ln_b, lat16);
  k_conv<<<dim3(16384), dim3(256), 0, stream>>>(camera, conv1_w, conv1_b, w2g, conv2_b, convflat);
  k_cnnlin<<<dim3(512), dim3(256), 0, stream>>>(convflat, cnnWb, cnn_lin_b,
                                                cnn_ln_g, cnn_ln_b, lat16);
  k_router<<<dim3(512), dim3(256), 0, stream>>>(lat16, rw1, rb1, rw2, rb2, rw3, rb3, gate);
  k_experts<<<dim3(2048), dim3(256), 0, stream>>>(lat16, gate, wt1, wt2, wt3, w4t,
                                                  eb1, eb2, eb3, eb4, eout, 0);
  k_experts<<<dim3(2048), dim3(256), 0, stream>>>(lat16, gate, wt1, wt2, wt3, w4t,
                                                  eb1, eb2, eb3, eb4, eout, 8);
  k_reduce<<<dim3(768), dim3(256), 0, stream>>>(eout, out);
}